// Round 13
// baseline (144.011 us; speedup 1.0000x reference)
//
#include <hip/hip_runtime.h>
#include <math.h>

typedef _Float16 f16;
typedef __attribute__((ext_vector_type(4))) _Float16 f16x4;
typedef __attribute__((ext_vector_type(8))) _Float16 f16x8;
typedef __attribute__((ext_vector_type(2))) __fp16 h16x2;
typedef __attribute__((ext_vector_type(4))) __fp16 h16x4;
typedef __attribute__((ext_vector_type(4))) float f32x4;

__device__ __forceinline__ void load_lds16(const void* g, void* l) {
    __builtin_amdgcn_global_load_lds((const __attribute__((address_space(1))) void*)g,
                                     (__attribute__((address_space(3))) void*)l, 16, 0, 0);
}

__device__ __forceinline__ float fast_exp2(float x) {
#if __has_builtin(__builtin_amdgcn_exp2f)
    return __builtin_amdgcn_exp2f(x);
#else
    return __exp2f(x);
#endif
}

#define MFMA32(a, b, c) __builtin_amdgcn_mfma_f32_16x16x32_f16(a, b, c, 0, 0, 0)

// ---------------------------------------------------------------------------
// Kernel 1: QKV GEMM with fused x-transpose + register prefetch of k+1 tiles.
// ---------------------------------------------------------------------------
__global__ __launch_bounds__(256) void gemm_qkv(
        const float* __restrict__ A, const float* __restrict__ xg,
        f16* __restrict__ qb, f16* __restrict__ kb, f16* __restrict__ vb) {
    __shared__ __align__(16) char smem[41984];
    f16* As = (f16*)smem;                    // 128 x 64 f16 = 16 KB
    f16* Bs = (f16*)(smem + 16384);          // 64 x 64 f16  =  8 KB
    float* Xs = (float*)(smem + 24576);      // 64 x 68 fp32 = 17408 B
    const int K = 256, tid = threadIdx.x;
    const int w = tid >> 6, lane = tid & 63, l16 = lane & 15, g = lane >> 4;
    const int wm = w >> 1, wn = w & 1;
    const int mBase = blockIdx.y * 128, nBase = blockIdx.x * 64;
    const int swz = lane & 7;

    f32x4 acc[4][2] = {};
    const int srow = tid >> 1;
    const int sc0 = (tid & 1) * 4;
    const int xc = tid >> 2;
    const int xp = (tid & 3) * 16;
    const int tp = tid & 63;
    const int tc = (tid >> 6) * 2;

    float4 xr[4], ar[8];
    // prologue load k-tile 0
    for (int q = 0; q < 4; q++)
        xr[q] = *(const float4*)&xg[(size_t)(xc)*4096 + nBase + xp + q * 4];
    for (int cc = 0; cc < 4; cc++) {
        const float* ap = A + (size_t)(mBase + srow) * K + (sc0 + cc) * 8;
        ar[cc * 2] = *(const float4*)ap;
        ar[cc * 2 + 1] = *(const float4*)(ap + 4);
    }

    for (int kt = 0; kt < 4; kt++) {
        // store phase (from regs)
        for (int q = 0; q < 4; q++)
            *(float4*)&Xs[xc * 68 + xp + q * 4] = xr[q];
        for (int cc = 0; cc < 4; cc++) {
            const int c = sc0 + cc;
            float4 u0 = ar[cc * 2], u1 = ar[cc * 2 + 1];
            f16x8 hv;
            hv[0] = (f16)u0.x; hv[1] = (f16)u0.y; hv[2] = (f16)u0.z; hv[3] = (f16)u0.w;
            hv[4] = (f16)u1.x; hv[5] = (f16)u1.y; hv[6] = (f16)u1.z; hv[7] = (f16)u1.w;
            *(f16x8*)&As[srow * 64 + ((c ^ (srow & 7)) * 8)] = hv;
        }
        __syncthreads();
        // transpose Xs -> Bs
        for (int cc = 0; cc < 2; cc++) {
            const int c8 = tc + cc;
            f16x8 hv;
            for (int e = 0; e < 8; e++)
                hv[e] = (f16)Xs[(c8 * 8 + e) * 68 + tp];
            *(f16x8*)&Bs[tp * 64 + ((c8 ^ (tp & 7)) * 8)] = hv;
        }
        // issue k+1 global loads (overlap with rest of this iter)
        if (kt < 3) {
            const int k0n = (kt + 1) * 64;
            for (int q = 0; q < 4; q++)
                xr[q] = *(const float4*)&xg[(size_t)(k0n + xc) * 4096 + nBase + xp + q * 4];
            for (int cc = 0; cc < 4; cc++) {
                const float* ap = A + (size_t)(mBase + srow) * K + k0n + (sc0 + cc) * 8;
                ar[cc * 2] = *(const float4*)ap;
                ar[cc * 2 + 1] = *(const float4*)(ap + 4);
            }
        }
        __syncthreads();
        for (int ks = 0; ks < 2; ks++) {
            const int ch = ((ks * 4 + g) ^ swz) * 8;
            f16x8 af[4], bf[2];
            for (int t = 0; t < 4; t++)
                af[t] = *(const f16x8*)&As[(wm * 64 + t * 16 + l16) * 64 + ch];
            for (int t = 0; t < 2; t++)
                bf[t] = *(const f16x8*)&Bs[(wn * 32 + t * 16 + l16) * 64 + ch];
            for (int mt = 0; mt < 4; mt++)
                for (int nt = 0; nt < 2; nt++)
                    acc[mt][nt] = MFMA32(af[mt], bf[nt], acc[mt][nt]);
        }
        __syncthreads();
    }

    const int which = mBase >> 9;  // 0=q, 1=k, 2=v
    if (which < 2) {
        const float sc = (which == 0) ? 0.18033688011112042f : 1.0f;  // 0.125*log2e
        f16* Ts = (f16*)smem;  // 64 x 136
        for (int mt = 0; mt < 4; mt++)
            for (int nt = 0; nt < 2; nt++)
                for (int r = 0; r < 4; r++)
                    Ts[(wn * 32 + nt * 16 + l16) * 136 + wm * 64 + mt * 16 + g * 4 + r] =
                        (f16)(acc[mt][nt][r] * sc);
        __syncthreads();
        f16* tgt = (which == 0) ? qb : kb;
        const int row = tid >> 2;
        const int p = nBase + row;
        for (int cc = 0; cc < 4; cc++) {
            const int c8 = (tid & 3) * 4 + cc;
            f16x8 v = *(const f16x8*)&Ts[row * 136 + c8 * 8];
            const int o = mBase + c8 * 8;
            const int head = (o >> 6) & 7;
            const int d = o & 63;
            *(f16x8*)&tgt[(size_t)head * 262144 + (size_t)p * 64 + d] = v;
        }
    } else {
        for (int mt = 0; mt < 4; mt++)
            for (int nt = 0; nt < 2; nt++)
                for (int r = 0; r < 4; r++) {
                    const int o = mBase + wm * 64 + mt * 16 + g * 4 + r;
                    const int p = nBase + wn * 32 + nt * 16 + l16;
                    const int vd = o - 1024;
                    vb[(size_t)(vd >> 6) * 262144 + (size_t)(vd & 63) * 4096 + p] =
                        (f16)acc[mt][nt][r];
                }
    }
}

// ---------------------------------------------------------------------------
// Kernel 2: flash attention — all-MFMA32, 32 i-rows/wave, grid 1024
// (8h x 32it x 4s) -> 3 blocks/CU, 12 waves. P via wave-private LDS buffer,
// 2-stage pipelined (write P(0),P(1) then PV(0),PV(1)) to hide ds latency.
// ---------------------------------------------------------------------------
__global__ __launch_bounds__(256, 3) void attn_fwd(
        const f16* __restrict__ qb, const f16* __restrict__ kb,
        const f16* __restrict__ vb, f16* __restrict__ Op, float* __restrict__ Lp) {
    __shared__ __align__(16) char smem[51200];
    f16* Ks = (f16*)smem;                  // 2 x 8KB
    f16* Vs = (f16*)(smem + 16384);        // 2 x 8KB
    f16* Pb = (f16*)(smem + 32768);        // 4 waves x 2 stages x 2 ib x 16 x 72B
    const int tid = threadIdx.x;
    const int w = tid >> 6, lane = tid & 63, l16 = lane & 15, g = lane >> 4;
    const int bx = blockIdx.x;
    const int h = bx & 7, rest = bx >> 3, it = rest >> 2, s = rest & 3;
    const f16* Qw = qb + (size_t)h * 262144 + (size_t)(it * 128 + w * 32) * 64;
    const f16* Kh = kb + (size_t)h * 262144 + (size_t)s * 65536;   // [j][d]
    const f16* Vh = vb + (size_t)h * 262144 + (size_t)s * 1024;    // [d][j]

    f16x8 aq[2][2];
#pragma unroll
    for (int ib = 0; ib < 2; ib++)
#pragma unroll
        for (int ks = 0; ks < 2; ks++)
            aq[ib][ks] = *(const f16x8*)(Qw + (ib * 16 + l16) * 64 + ks * 32 + g * 8);

    const int L0 = w * 64 + lane, L1 = 256 + w * 64 + lane;
    const int r0 = L0 >> 3, r1 = L1 >> 3;
    const int kO0 = r0 * 64 + (((L0 & 7) ^ (r0 & 7)) * 8);
    const int kO1 = r1 * 64 + (((L1 & 7) ^ (r1 & 7)) * 8);
    const int vO0 = r0 * 4096 + (((L0 & 7) ^ (r0 & 7)) * 8);
    const int vO1 = r1 * 4096 + (((L1 & 7) ^ (r1 & 7)) * 8);

    load_lds16(Kh + kO0, &Ks[L0 * 8]);
    load_lds16(Kh + kO1, &Ks[L1 * 8]);
    load_lds16(Vh + vO0, &Vs[L0 * 8]);
    load_lds16(Vh + vO1, &Vs[L1 * 8]);
    __syncthreads();

    f32x4 oacc[2][4] = {};
    float lsum[2] = {0.f, 0.f};
    const h16x2 one2 = {(__fp16)1.0f, (__fp16)1.0f};
    const f16* Kp0 = Ks + l16 * 64 + ((g ^ (l16 & 7)) * 8);
    const f16* Kp1 = Ks + l16 * 64 + (((g ^ 4) ^ (l16 & 7)) * 8);
    f16* Pw = Pb + w * 2304;                 // per-wave, 2 stages x 2 ib x 16 x 36
    f16* PwW = Pw + l16 * 36 + g * 4;
    const f16* PwR = Pw + l16 * 36 + g * 8;

#pragma unroll
    for (int jt = 0; jt < 16; jt++) {
        const int cur = jt & 1;
        if (jt < 15) {
            const int nxt = cur ^ 1;
            const f16* Kt = Kh + (jt + 1) * 4096;
            const f16* Vt = Vh + (jt + 1) * 64;
            load_lds16(Kt + kO0, &Ks[nxt * 4096 + L0 * 8]);
            load_lds16(Kt + kO1, &Ks[nxt * 4096 + L1 * 8]);
            load_lds16(Vt + vO0, &Vs[nxt * 4096 + L0 * 8]);
            load_lds16(Vt + vO1, &Vs[nxt * 4096 + L1 * 8]);
        }
        // phase 1: QK + exp + write P for both ntp stages
#pragma unroll
        for (int ntp = 0; ntp < 2; ntp++) {
            const int nt0 = ntp * 2, nt1 = ntp * 2 + 1;
            f16x8 kf00 = *(const f16x8*)(Kp0 + cur * 4096 + nt0 * 1024);
            f16x8 kf01 = *(const f16x8*)(Kp1 + cur * 4096 + nt0 * 1024);
            f16x8 kf10 = *(const f16x8*)(Kp0 + cur * 4096 + nt1 * 1024);
            f16x8 kf11 = *(const f16x8*)(Kp1 + cur * 4096 + nt1 * 1024);
#pragma unroll
            for (int ib = 0; ib < 2; ib++) {
                f32x4 sa = {}, sb = {};
                sa = MFMA32(kf00, aq[ib][0], sa);
                sa = MFMA32(kf01, aq[ib][1], sa);
                sb = MFMA32(kf10, aq[ib][0], sb);
                sb = MFMA32(kf11, aq[ib][1], sb);
                h16x2 a01 = __builtin_amdgcn_cvt_pkrtz(fast_exp2(sa[0]), fast_exp2(sa[1]));
                h16x2 a23 = __builtin_amdgcn_cvt_pkrtz(fast_exp2(sa[2]), fast_exp2(sa[3]));
                h16x2 b01 = __builtin_amdgcn_cvt_pkrtz(fast_exp2(sb[0]), fast_exp2(sb[1]));
                h16x2 b23 = __builtin_amdgcn_cvt_pkrtz(fast_exp2(sb[2]), fast_exp2(sb[3]));
                lsum[ib] = __builtin_amdgcn_fdot2(a01, one2, lsum[ib], false);
                lsum[ib] = __builtin_amdgcn_fdot2(a23, one2, lsum[ib], false);
                lsum[ib] = __builtin_amdgcn_fdot2(b01, one2, lsum[ib], false);
                lsum[ib] = __builtin_amdgcn_fdot2(b23, one2, lsum[ib], false);
                f16x4 apA = __builtin_bit_cast(f16x4, __builtin_shufflevector(a01, a23, 0, 1, 2, 3));
                f16x4 apB = __builtin_bit_cast(f16x4, __builtin_shufflevector(b01, b23, 0, 1, 2, 3));
                *(f16x4*)(PwW + ntp * 1152 + ib * 576) = apA;
                *(f16x4*)(PwW + ntp * 1152 + ib * 576 + 16) = apB;
            }
        }
        // phase 2: PV for both stages (P writes aged by a full QK/exp burst)
#pragma unroll
        for (int ntp = 0; ntp < 2; ntp++) {
            f16x8 bv[4];
#pragma unroll
            for (int dn = 0; dn < 4; dn++)
                bv[dn] = *(const f16x8*)&Vs[cur * 4096 + (dn * 16 + l16) * 64 +
                                            (((ntp * 4 + g) ^ (l16 & 7)) * 8)];
#pragma unroll
            for (int ib = 0; ib < 2; ib++) {
                f16x4 lo = *(const f16x4*)(PwR + ntp * 1152 + ib * 576);
                f16x4 hi = *(const f16x4*)(PwR + ntp * 1152 + ib * 576 + 4);
                f16x8 a8 = __builtin_shufflevector(lo, hi, 0, 1, 2, 3, 4, 5, 6, 7);
#pragma unroll
                for (int dn = 0; dn < 4; dn++)
                    oacc[ib][dn] = MFMA32(a8, bv[dn], oacc[ib][dn]);
            }
        }
        __syncthreads();
    }
#pragma unroll
    for (int ib = 0; ib < 2; ib++) {
        lsum[ib] += __shfl_xor(lsum[ib], 16);
        lsum[ib] += __shfl_xor(lsum[ib], 32);
    }
    if (lane < 16)
#pragma unroll
        for (int ib = 0; ib < 2; ib++)
            Lp[(size_t)s * 32768 + (size_t)(it * 128 + w * 32 + ib * 16 + l16) * 8 + h] =
                lsum[ib];
    f16* Oh = Op + (size_t)s * 2097152 + (size_t)(it * 128 + w * 32) * 512 + h * 64;
#pragma unroll
    for (int ib = 0; ib < 2; ib++)
        for (int dn = 0; dn < 4; dn++)
            for (int r = 0; r < 4; r++) {
                const int i = ib * 16 + g * 4 + r;
                Oh[(size_t)i * 512 + dn * 16 + l16] = (f16)oacc[ib][dn][r];
            }
}

// ---------------------------------------------------------------------------
// Kernel 3: out GEMM with fused combine + register prefetch of k+1 tiles.
// ---------------------------------------------------------------------------
__global__ __launch_bounds__(256) void gemm_out(
        const float* __restrict__ A, const f16* __restrict__ Op,
        const float* __restrict__ Lp, const float* __restrict__ bias,
        float* __restrict__ C) {
    __shared__ __align__(16) char smem[13312];
    f16* As = (f16*)smem;                  // 64 x 64
    f16* Bs = (f16*)(smem + 8192);         // 32 x 64
    float* invL = (float*)(smem + 12288);  // 32 p x 8 h
    const int tid = threadIdx.x;
    const int w = tid >> 6, lane = tid & 63, l16 = lane & 15, g = lane >> 4;
    const int wm = w >> 1, wn = w & 1;
    const int mBase = blockIdx.y * 64, nBase = blockIdx.x * 32;
    const int swz = lane & 7;

    {
        const int p = nBase + (tid >> 3), hh = tid & 7;
        float sum = 0.f;
        for (int s4 = 0; s4 < 4; s4++) sum += Lp[(size_t)s4 * 32768 + p * 8 + hh];
        invL[tid] = 1.0f / sum;
    }

    f32x4 acc[2] = {};
    const int srow = tid >> 2;
    const int sc0 = (tid & 3) * 2;
    const int brow = tid >> 3;
    const int bgc = (tid & 7) ^ (brow & 7);

    float4 ar[4];
    f16x8 br[4];
    // prologue: k-tile 0
    for (int cc = 0; cc < 2; cc++) {
        const float* ap = A + (size_t)(mBase + srow) * 512 + (sc0 + cc) * 8;
        ar[cc * 2] = *(const float4*)ap;
        ar[cc * 2 + 1] = *(const float4*)(ap + 4);
    }
    {
        const f16* op0 = Op + (size_t)(nBase + brow) * 512 + bgc * 8;
        br[0] = *(const f16x8*)(op0);
        br[1] = *(const f16x8*)(op0 + 2097152);
        br[2] = *(const f16x8*)(op0 + 4194304);
        br[3] = *(const f16x8*)(op0 + 6291456);
    }
    __syncthreads();  // invL ready

    for (int kt = 0; kt < 8; kt++) {
        // store phase
        for (int cc = 0; cc < 2; cc++) {
            const int c = sc0 + cc;
            float4 u0 = ar[cc * 2], u1 = ar[cc * 2 + 1];
            f16x8 hv;
            hv[0] = (f16)u0.x; hv[1] = (f16)u0.y; hv[2] = (f16)u0.z; hv[3] = (f16)u0.w;
            hv[4] = (f16)u1.x; hv[5] = (f16)u1.y; hv[6] = (f16)u1.z; hv[7] = (f16)u1.w;
            *(f16x8*)&As[srow * 64 + ((c ^ (srow & 7)) * 8)] = hv;
        }
        {
            const f16 iv = (f16)invL[brow * 8 + kt];
            f16x8 bsum = (br[0] + br[1]) + (br[2] + br[3]);
            bsum = bsum * iv;
            *(f16x8*)&Bs[tid * 8] = bsum;
        }
        __syncthreads();
        // prefetch k+1 (overlaps MFMA)
        if (kt < 7) {
            const int k0n = (kt + 1) * 64;
            for (int cc = 0; cc < 2; cc++) {
                const float* ap = A + (size_t)(mBase + srow) * 512 + k0n + (sc0 + cc) * 8;
                ar[cc * 2] = *(const float4*)ap;
                ar[cc * 2 + 1] = *(const float4*)(ap + 4);
            }
            const f16* op0 = Op + (size_t)(nBase + brow) * 512 + k0n + bgc * 8;
            br[0] = *(const f16x8*)(op0);
            br[1] = *(const f16x8*)(op0 + 2097152);
            br[2] = *(const f16x8*)(op0 + 4194304);
            br[3] = *(const f16x8*)(op0 + 6291456);
        }
        for (int ks = 0; ks < 2; ks++) {
            const int chv = ((ks * 4 + g) ^ swz) * 8;
            f16x8 af[2], bf;
            for (int t = 0; t < 2; t++)
                af[t] = *(const f16x8*)&As[(wm * 32 + t * 16 + l16) * 64 + chv];
            bf = *(const f16x8*)&Bs[(wn * 16 + l16) * 64 + chv];
            for (int mt = 0; mt < 2; mt++)
                acc[mt] = MFMA32(af[mt], bf, acc[mt]);
        }
        __syncthreads();
    }

    for (int mt = 0; mt < 2; mt++)
        for (int r = 0; r < 4; r++) {
            const int o = mBase + wm * 32 + mt * 16 + g * 4 + r;
            const float bb = bias[o];
            const int p = nBase + wn * 16 + l16;
            C[(size_t)o * 4096 + p] = acc[mt][r] + bb;
        }
}

// ---------------------------------------------------------------------------
extern "C" void kernel_launch(void* const* d_in, const int* in_sizes, int n_in,
                              void* d_out, int out_size, void* d_ws, size_t ws_size,
                              hipStream_t stream) {
    const float* x    = (const float*)d_in[0];  // (1,256,64,64)
    const float* wqkv = (const float*)d_in[1];  // (1536,256)
    const float* wout = (const float*)d_in[2];  // (256,512)
    const float* bout = (const float*)d_in[3];  // (256,)
    float* out = (float*)d_out;                 // (1,256,64,64)

    char* ws = (char*)d_ws;
    float* Lp = (float*)(ws);                    // [0,512K)
    f16* qb = (f16*)(ws + (2u << 20));           // [2M,6M)
    f16* kb = (f16*)(ws + (6u << 20));           // [6M,10M)
    f16* vb = (f16*)(ws + (10u << 20));          // [10M,14M) [head][d][p]
    f16* Op = (f16*)(ws + (14u << 20));          // [14M,30M) 4 split quarters

    gemm_qkv<<<dim3(64, 12), 256, 0, stream>>>(wqkv, x, qb, kb, vb);
    attn_fwd<<<dim3(1024), 256, 0, stream>>>(qb, kb, vb, Op, Lp);
    gemm_out<<<dim3(128, 4), 256, 0, stream>>>(wout, Op, Lp, bout, out);
}

// Round 14
// 132.798 us; speedup vs baseline: 1.0844x; 1.0844x over previous
//
#include <hip/hip_runtime.h>
#include <math.h>

typedef _Float16 f16;
typedef __attribute__((ext_vector_type(4))) _Float16 f16x4;
typedef __attribute__((ext_vector_type(8))) _Float16 f16x8;
typedef __attribute__((ext_vector_type(2))) __fp16 h16x2;
typedef __attribute__((ext_vector_type(4))) __fp16 h16x4;
typedef __attribute__((ext_vector_type(4))) float f32x4;

__device__ __forceinline__ void load_lds16(const void* g, void* l) {
    __builtin_amdgcn_global_load_lds((const __attribute__((address_space(1))) void*)g,
                                     (__attribute__((address_space(3))) void*)l, 16, 0, 0);
}

__device__ __forceinline__ float fast_exp2(float x) {
#if __has_builtin(__builtin_amdgcn_exp2f)
    return __builtin_amdgcn_exp2f(x);
#else
    return __exp2f(x);
#endif
}

#define MFMA32(a, b, c) __builtin_amdgcn_mfma_f32_16x16x32_f16(a, b, c, 0, 0, 0)

// ---------------------------------------------------------------------------
// Kernel 1: x[c][p] fp32 -> xh[p][c] fp16   (c=256, p=4096)
// ---------------------------------------------------------------------------
__global__ __launch_bounds__(256) void kxpose(const float* __restrict__ x,
                                              f16* __restrict__ xh) {
    __shared__ f16 t[64][65];
    const int p0 = blockIdx.x * 64;
    const int c0 = blockIdx.y * 64;
    const int lp = threadIdx.x & 63;
    const int lq = threadIdx.x >> 6;
    for (int i = 0; i < 64; i += 4)
        t[i + lq][lp] = (f16)x[(size_t)(c0 + i + lq) * 4096 + p0 + lp];
    __syncthreads();
    for (int i = 0; i < 64; i += 4)
        xh[(size_t)(p0 + i + lq) * 256 + c0 + lp] = t[lp][i + lq];
}

// ---------------------------------------------------------------------------
// Kernel 2: QKV GEMM, BM=BN=128 (grid 32x12), B via global_load_lds from xh.
// Epilogues: q/k -> [head][p][d] via Ts transpose (q pre-scaled 0.125*log2e);
//            v   -> [head][d][p] direct from acc C-layout.
// ---------------------------------------------------------------------------
__global__ __launch_bounds__(256) void gemm_qkv(
        const float* __restrict__ A, const f16* __restrict__ B,
        f16* __restrict__ qb, f16* __restrict__ kb, f16* __restrict__ vb) {
    __shared__ __align__(16) char smem[32768];
    f16* As = (f16*)smem;
    f16* Bs = (f16*)(smem + 16384);
    const int K = 256, tid = threadIdx.x;
    const int w = tid >> 6, lane = tid & 63, l16 = lane & 15, g = lane >> 4;
    const int wm = w >> 1, wn = w & 1;
    const int mBase = blockIdx.y * 128, nBase = blockIdx.x * 128;
    const int swz = lane & 7;

    f32x4 acc[4][4] = {};
    const int srow = tid >> 1;
    const int sc0 = (tid & 1) * 4;

    for (int k0 = 0; k0 < K; k0 += 64) {
        for (int cc = 0; cc < 4; cc++) {
            const int c = sc0 + cc;
            const float* ap = A + (size_t)(mBase + srow) * K + k0 + c * 8;
            float4 u0 = *(const float4*)ap;
            float4 u1 = *(const float4*)(ap + 4);
            f16x8 hv;
            hv[0] = (f16)u0.x; hv[1] = (f16)u0.y; hv[2] = (f16)u0.z; hv[3] = (f16)u0.w;
            hv[4] = (f16)u1.x; hv[5] = (f16)u1.y; hv[6] = (f16)u1.z; hv[7] = (f16)u1.w;
            *(f16x8*)&As[srow * 64 + ((c ^ (srow & 7)) * 8)] = hv;
        }
        for (int c = 0; c < 4; c++) {
            const int L = c * 256 + w * 64 + lane;
            const int row = L >> 3;
            load_lds16(B + (size_t)(nBase + row) * K + k0 + (((lane & 7) ^ (row & 7)) * 8),
                       &Bs[(c * 256 + w * 64) * 8]);
        }
        __syncthreads();
        for (int ks = 0; ks < 2; ks++) {
            const int ch = ((ks * 4 + g) ^ swz) * 8;
            f16x8 af[4], bf[4];
            for (int t = 0; t < 4; t++)
                af[t] = *(const f16x8*)&As[(wm * 64 + t * 16 + l16) * 64 + ch];
            for (int t = 0; t < 4; t++)
                bf[t] = *(const f16x8*)&Bs[(wn * 64 + t * 16 + l16) * 64 + ch];
            for (int mt = 0; mt < 4; mt++)
                for (int nt = 0; nt < 4; nt++)
                    acc[mt][nt] = MFMA32(af[mt], bf[nt], acc[mt][nt]);
        }
        __syncthreads();
    }

    const int which = mBase >> 9;  // 0=q, 1=k, 2=v (block-uniform)
    if (which == 2) {
        // V: direct from C-layout into [head][d][p]
        for (int mt = 0; mt < 4; mt++)
            for (int nt = 0; nt < 4; nt++)
                for (int r = 0; r < 4; r++) {
                    const int o = mBase + wm * 64 + mt * 16 + g * 4 + r;
                    const int p = nBase + wn * 64 + nt * 16 + l16;
                    const int vd = o - 1024;
                    vb[(size_t)(vd >> 6) * 262144 + (size_t)(vd & 63) * 4096 + p] =
                        (f16)acc[mt][nt][r];
                }
    } else {
        f16* tgt = (which == 0) ? qb : kb;
        const float sc = (which == 0) ? 0.18033688011112042f : 1.0f;  // 0.125*log2e
        f16* Ts = (f16*)smem;  // 64 x stride-136 = 17408 B
        for (int ph = 0; ph < 2; ph++) {
            __syncthreads();
            if (wn == ph) {
                for (int mt = 0; mt < 4; mt++)
                    for (int nt = 0; nt < 4; nt++)
                        for (int r = 0; r < 4; r++)
                            Ts[(nt * 16 + l16) * 136 + wm * 64 + mt * 16 + g * 4 + r] =
                                (f16)(acc[mt][nt][r] * sc);
            }
            __syncthreads();
            const int row = tid >> 2;                 // p within half
            const int p = nBase + ph * 64 + row;
            for (int cc = 0; cc < 4; cc++) {
                const int c8 = (tid & 3) * 4 + cc;    // 8-f16 chunk of o
                f16x8 v = *(const f16x8*)&Ts[row * 136 + c8 * 8];
                const int o = mBase + c8 * 8;
                const int head = (o >> 6) & 7;
                const int d = o & 63;
                *(f16x8*)&tgt[(size_t)head * 262144 + (size_t)p * 64 + d] = v;
            }
        }
    }
}

// ---------------------------------------------------------------------------
// Kernel 3: flash attention — all-MFMA32 (K=32 PV via wave-private P buffer).
// R12-exact. grid 512 = 8h x 16it x 4s; 64 i-rows/wave.
// ---------------------------------------------------------------------------
__global__ __launch_bounds__(256, 2) void attn_fwd(
        const f16* __restrict__ qb, const f16* __restrict__ kb,
        const f16* __restrict__ vb, f16* __restrict__ Op, float* __restrict__ Lp) {
    __shared__ __align__(16) char smem[51200];
    f16* Ks = (f16*)smem;                  // 2 x 8KB double buffer
    f16* Vs = (f16*)(smem + 16384);        // 2 x 8KB double buffer
    f16* Pb = (f16*)(smem + 32768);        // 4 waves x 64 rows x 72B
    const int tid = threadIdx.x;
    const int w = tid >> 6, lane = tid & 63, l16 = lane & 15, g = lane >> 4;
    const int bx = blockIdx.x;
    const int h = bx & 7, rest = bx >> 3, it = rest >> 2, s = rest & 3;
    const f16* Qw = qb + (size_t)h * 262144 + (size_t)(it * 256 + w * 64) * 64;
    const f16* Kh = kb + (size_t)h * 262144 + (size_t)s * 65536;   // [j][d]
    const f16* Vh = vb + (size_t)h * 262144 + (size_t)s * 1024;    // [d][j]

    f16x8 aq[4][2];
#pragma unroll
    for (int ib = 0; ib < 4; ib++)
#pragma unroll
        for (int ks = 0; ks < 2; ks++)
            aq[ib][ks] = *(const f16x8*)(Qw + (ib * 16 + l16) * 64 + ks * 32 + g * 8);

    const int L0 = w * 64 + lane, L1 = 256 + w * 64 + lane;
    const int r0 = L0 >> 3, r1 = L1 >> 3;
    const int kO0 = r0 * 64 + (((L0 & 7) ^ (r0 & 7)) * 8);
    const int kO1 = r1 * 64 + (((L1 & 7) ^ (r1 & 7)) * 8);
    const int vO0 = r0 * 4096 + (((L0 & 7) ^ (r0 & 7)) * 8);
    const int vO1 = r1 * 4096 + (((L1 & 7) ^ (r1 & 7)) * 8);

    load_lds16(Kh + kO0, &Ks[L0 * 8]);
    load_lds16(Kh + kO1, &Ks[L1 * 8]);
    load_lds16(Vh + vO0, &Vs[L0 * 8]);
    load_lds16(Vh + vO1, &Vs[L1 * 8]);
    __syncthreads();

    f32x4 oacc[4][4] = {};
    float lsum[4] = {0.f, 0.f, 0.f, 0.f};
    const h16x2 one2 = {(__fp16)1.0f, (__fp16)1.0f};
    const f16* Kp0 = Ks + l16 * 64 + ((g ^ (l16 & 7)) * 8);
    const f16* Kp1 = Ks + l16 * 64 + (((g ^ 4) ^ (l16 & 7)) * 8);
    f16* Pw = Pb + w * 2304;                 // 64 rows x 36 f16 (72 B)
    f16* PwW = Pw + l16 * 36 + g * 4;
    const f16* PwR = Pw + l16 * 36 + g * 8;

#pragma unroll
    for (int jt = 0; jt < 16; jt++) {
        const int cur = jt & 1;
        if (jt < 15) {
            const int nxt = cur ^ 1;
            const f16* Kt = Kh + (jt + 1) * 4096;
            const f16* Vt = Vh + (jt + 1) * 64;
            load_lds16(Kt + kO0, &Ks[nxt * 4096 + L0 * 8]);
            load_lds16(Kt + kO1, &Ks[nxt * 4096 + L1 * 8]);
            load_lds16(Vt + vO0, &Vs[nxt * 4096 + L0 * 8]);
            load_lds16(Vt + vO1, &Vs[nxt * 4096 + L1 * 8]);
        }
#pragma unroll
        for (int ntp = 0; ntp < 2; ntp++) {
            const int nt0 = ntp * 2, nt1 = ntp * 2 + 1;
            f16x8 kf00 = *(const f16x8*)(Kp0 + cur * 4096 + nt0 * 1024);
            f16x8 kf01 = *(const f16x8*)(Kp1 + cur * 4096 + nt0 * 1024);
            f16x8 kf10 = *(const f16x8*)(Kp0 + cur * 4096 + nt1 * 1024);
            f16x8 kf11 = *(const f16x8*)(Kp1 + cur * 4096 + nt1 * 1024);
#pragma unroll
            for (int ib = 0; ib < 4; ib++) {
                f32x4 sa = {}, sb = {};
                sa = MFMA32(kf00, aq[ib][0], sa);
                sa = MFMA32(kf01, aq[ib][1], sa);
                sb = MFMA32(kf10, aq[ib][0], sb);
                sb = MFMA32(kf11, aq[ib][1], sb);
                h16x2 a01 = __builtin_amdgcn_cvt_pkrtz(fast_exp2(sa[0]), fast_exp2(sa[1]));
                h16x2 a23 = __builtin_amdgcn_cvt_pkrtz(fast_exp2(sa[2]), fast_exp2(sa[3]));
                h16x2 b01 = __builtin_amdgcn_cvt_pkrtz(fast_exp2(sb[0]), fast_exp2(sb[1]));
                h16x2 b23 = __builtin_amdgcn_cvt_pkrtz(fast_exp2(sb[2]), fast_exp2(sb[3]));
                lsum[ib] = __builtin_amdgcn_fdot2(a01, one2, lsum[ib], false);
                lsum[ib] = __builtin_amdgcn_fdot2(a23, one2, lsum[ib], false);
                lsum[ib] = __builtin_amdgcn_fdot2(b01, one2, lsum[ib], false);
                lsum[ib] = __builtin_amdgcn_fdot2(b23, one2, lsum[ib], false);
                f16x4 apA = __builtin_bit_cast(f16x4, __builtin_shufflevector(a01, a23, 0, 1, 2, 3));
                f16x4 apB = __builtin_bit_cast(f16x4, __builtin_shufflevector(b01, b23, 0, 1, 2, 3));
                *(f16x4*)(PwW + ib * 576) = apA;
                *(f16x4*)(PwW + ib * 576 + 16) = apB;
            }
            f16x8 bv[4];
#pragma unroll
            for (int dn = 0; dn < 4; dn++)
                bv[dn] = *(const f16x8*)&Vs[cur * 4096 + (dn * 16 + l16) * 64 +
                                            (((ntp * 4 + g) ^ (l16 & 7)) * 8)];
#pragma unroll
            for (int ib = 0; ib < 4; ib++) {
                f16x4 lo = *(const f16x4*)(PwR + ib * 576);
                f16x4 hi = *(const f16x4*)(PwR + ib * 576 + 4);
                f16x8 a8 = __builtin_shufflevector(lo, hi, 0, 1, 2, 3, 4, 5, 6, 7);
#pragma unroll
                for (int dn = 0; dn < 4; dn++)
                    oacc[ib][dn] = MFMA32(a8, bv[dn], oacc[ib][dn]);
            }
        }
        __syncthreads();
    }
#pragma unroll
    for (int ib = 0; ib < 4; ib++) {
        lsum[ib] += __shfl_xor(lsum[ib], 16);
        lsum[ib] += __shfl_xor(lsum[ib], 32);
    }
    if (lane < 16)
#pragma unroll
        for (int ib = 0; ib < 4; ib++)
            Lp[(size_t)s * 32768 + (size_t)(it * 256 + w * 64 + ib * 16 + l16) * 8 + h] =
                lsum[ib];
    f16* Oh = Op + (size_t)s * 2097152 + (size_t)(it * 256 + w * 64) * 512 + h * 64;
#pragma unroll
    for (int ib = 0; ib < 4; ib++)
        for (int dn = 0; dn < 4; dn++)
            for (int r = 0; r < 4; r++) {
                const int i = ib * 16 + g * 4 + r;
                Oh[(size_t)i * 512 + dn * 16 + l16] = (f16)oacc[ib][dn][r];
            }
}

// ---------------------------------------------------------------------------
// Kernel 4: out GEMM with fused combine, BM=BN=64, grid (64,4).
// ---------------------------------------------------------------------------
__global__ __launch_bounds__(256) void gemm_out(
        const float* __restrict__ A, const f16* __restrict__ Op,
        const float* __restrict__ Lp, const float* __restrict__ bias,
        float* __restrict__ C) {
    __shared__ __align__(16) char smem[18432];
    f16* As = (f16*)smem;                  // 8 KB
    f16* Bs = (f16*)(smem + 8192);         // 8 KB
    float* invL = (float*)(smem + 16384);  // 64 p x 8 h
    const int tid = threadIdx.x;
    const int w = tid >> 6, lane = tid & 63, l16 = lane & 15, g = lane >> 4;
    const int wm = w >> 1, wn = w & 1;
    const int mBase = blockIdx.y * 64, nBase = blockIdx.x * 64;
    const int swz = lane & 7;

    for (int e = 0; e < 2; e++) {
        const int idx = tid * 2 + e;           // p_loc*8 + h
        const int p = nBase + (idx >> 3), hh = idx & 7;
        float sum = 0.f;
        for (int s4 = 0; s4 < 4; s4++) sum += Lp[(size_t)s4 * 32768 + p * 8 + hh];
        invL[idx] = 1.0f / sum;
    }
    __syncthreads();

    f32x4 acc[2][2] = {};
    const int srow = tid >> 2;
    const int sc0 = (tid & 3) * 2;

    for (int k0 = 0; k0 < 512; k0 += 64) {
        for (int cc = 0; cc < 2; cc++) {
            const int c = sc0 + cc;
            const float* ap = A + (size_t)(mBase + srow) * 512 + k0 + c * 8;
            float4 u0 = *(const float4*)ap;
            float4 u1 = *(const float4*)(ap + 4);
            f16x8 hv;
            hv[0] = (f16)u0.x; hv[1] = (f16)u0.y; hv[2] = (f16)u0.z; hv[3] = (f16)u0.w;
            hv[4] = (f16)u1.x; hv[5] = (f16)u1.y; hv[6] = (f16)u1.z; hv[7] = (f16)u1.w;
            *(f16x8*)&As[srow * 64 + ((c ^ (srow & 7)) * 8)] = hv;
        }
        const int hk = k0 >> 6;               // head for this k-tile (uniform)
        for (int c = 0; c < 2; c++) {
            const int L = c * 256 + tid;
            const int row = L >> 3, ch = L & 7;
            const int gc = ch ^ (row & 7);
            const f16* op0 = Op + (size_t)(nBase + row) * 512 + k0 + gc * 8;
            f16x8 b0 = *(const f16x8*)(op0);
            f16x8 b1 = *(const f16x8*)(op0 + 2097152);
            f16x8 b2 = *(const f16x8*)(op0 + 4194304);
            f16x8 b3 = *(const f16x8*)(op0 + 6291456);
            const f16 iv = (f16)invL[row * 8 + hk];
            f16x8 bsum = (b0 + b1) + (b2 + b3);
            bsum = bsum * iv;
            *(f16x8*)&Bs[L * 8] = bsum;
        }
        __syncthreads();
        for (int ks = 0; ks < 2; ks++) {
            const int chv = ((ks * 4 + g) ^ swz) * 8;
            f16x8 af[2], bf[2];
            for (int t = 0; t < 2; t++)
                af[t] = *(const f16x8*)&As[(wm * 32 + t * 16 + l16) * 64 + chv];
            for (int t = 0; t < 2; t++)
                bf[t] = *(const f16x8*)&Bs[(wn * 32 + t * 16 + l16) * 64 + chv];
            for (int mt = 0; mt < 2; mt++)
                for (int nt = 0; nt < 2; nt++)
                    acc[mt][nt] = MFMA32(af[mt], bf[nt], acc[mt][nt]);
        }
        __syncthreads();
    }

    for (int mt = 0; mt < 2; mt++)
        for (int r = 0; r < 4; r++) {
            const int o = mBase + wm * 32 + mt * 16 + g * 4 + r;
            const float bb = bias[o];
            for (int nt = 0; nt < 2; nt++) {
                const int p = nBase + wn * 32 + nt * 16 + l16;
                C[(size_t)o * 4096 + p] = acc[mt][nt][r] + bb;
            }
        }
}

// ---------------------------------------------------------------------------
extern "C" void kernel_launch(void* const* d_in, const int* in_sizes, int n_in,
                              void* d_out, int out_size, void* d_ws, size_t ws_size,
                              hipStream_t stream) {
    const float* x    = (const float*)d_in[0];  // (1,256,64,64)
    const float* wqkv = (const float*)d_in[1];  // (1536,256)
    const float* wout = (const float*)d_in[2];  // (256,512)
    const float* bout = (const float*)d_in[3];  // (256,)
    float* out = (float*)d_out;                 // (1,256,64,64)

    char* ws = (char*)d_ws;
    float* Lp = (float*)(ws);                    // [0,512K) written by attn
    f16* qb = (f16*)(ws + (2u << 20));           // [2M,6M)
    f16* kb = (f16*)(ws + (6u << 20));           // [6M,10M)
    f16* vb = (f16*)(ws + (10u << 20));          // [10M,14M) [head][d][p]
    f16* Op = (f16*)(ws + (14u << 20));          // [14M,30M) 4 split quarters
    f16* xh = (f16*)(ws + (30u << 20));          // [30M,32M) transposed x

    kxpose<<<dim3(64, 4), 256, 0, stream>>>(x, xh);
    gemm_qkv<<<dim3(32, 12), 256, 0, stream>>>(wqkv, xh, qb, kb, vb);
    attn_fwd<<<dim3(512), 256, 0, stream>>>(qb, kb, vb, Op, Lp);
    gemm_out<<<dim3(64, 4), 256, 0, stream>>>(wout, Op, Lp, bout, out);
}